// Round 7
// baseline (3238.127 us; speedup 1.0000x reference)
//
#include <hip/hip_runtime.h>

typedef unsigned int u32;
typedef unsigned short u16;
typedef unsigned long long u64;
typedef short s8 __attribute__((ext_vector_type(8)));   // 8 x bf16 (as i16)
typedef float f4 __attribute__((ext_vector_type(4)));
typedef u32 v4 __attribute__((ext_vector_type(4)));     // 16B asm load payload

#define B_SZ   1024
#define H_SZ   512
#define G4     2048
#define NSTEPS 64

// ws layout (bytes)
#define WS_XE     0u          // [64][1024][16] bf16  = 2097152
#define WS_W0C    2097152u    // [2048][32]  bf16     = 131072
#define WS_WIH1   2228224u    // [2048][512] bf16     = 2097152
#define WS_WHH0   4325376u    // [2048][512] bf16     = 2097152
#define WS_WHH1   6422528u    // [2048][512] bf16     = 2097152
#define WS_UP     8519680u    // [2048][512] bf16     = 2097152  (U = wih0[:,0] x wproj)
#define WS_H0S    10616832u   // [2][1024][512] bf16  = 2097152
#define WS_H1S    12713984u   // [2][1024][512] bf16  = 2097152
#define WS_YPART  14811136u   // [2][1024][64] f32    = 524288
#define WS_FLAGS  15335424u   // [4][64] u32          = 1024
#define WS_NEEDED 15336448u

// LDS layout (bytes); weight row stride 1040 (520 bf16: 2-way bank alias = free)
#define WSTRIDE   1040
#define LDS_WA1   0        // W_ih1 slice  32 x 1040
#define LDS_WA0   33280    // W_hh0 slice
#define LDS_WB1   66560    // W_hh1 slice
#define LDS_WBU   99840    // U slice
#define LDS_W0C   133120   // chunk0 weights 32 x 64B
#define LDS_YROW  135168   // f32[256]
#define LDS_HST   136192   // u16[256][8]
#define LDS_TOTAL 140288

__device__ __forceinline__ float bf2f(short s) {
  u32 u = ((u32)(u16)s) << 16; float f; __builtin_memcpy(&f, &u, 4); return f;
}
__device__ __forceinline__ short f2bf(float f) {
  u32 u; __builtin_memcpy(&u, &f, 4);
  u = (u + 0x7fffu + ((u >> 16) & 1u)) >> 16; return (short)u;
}
__device__ __forceinline__ float sigm(float x) { return 1.f / (1.f + __expf(-x)); }
__device__ __forceinline__ float tanh_(float x) {
  float ax = fminf(fabsf(x), 15.f);
  float e = __expf(2.f * ax);
  float r = (e - 1.f) / (e + 1.f);
  return x < 0.f ? -r : r;
}

__device__ __forceinline__ u64 ald(const u64* p) {
  return __hip_atomic_load(p, __ATOMIC_RELAXED, __HIP_MEMORY_SCOPE_AGENT);
}
__device__ __forceinline__ void ast(u64* p, u64 v) {
  __hip_atomic_store(p, v, __ATOMIC_RELAXED, __HIP_MEMORY_SCOPE_AGENT);
}
__device__ __forceinline__ u32 ald32(const u32* p) {
  return __hip_atomic_load(p, __ATOMIC_RELAXED, __HIP_MEMORY_SCOPE_AGENT);
}
__device__ __forceinline__ void ast32(u32* p, u32 v) {
  __hip_atomic_store(p, v, __ATOMIC_RELAXED, __HIP_MEMORY_SCOPE_AGENT);
}

// CACHEABLE 16B load (L2-cached; freshness guaranteed by per-phase acquire
// fence = buffer_inv in barrier_wait); async until WAITV.
#define LOADX4(dst, ptr, IMM) \
  asm volatile("global_load_dwordx4 %0, %1, off offset:" #IMM : "=v"(dst) : "v"(ptr))
#define WAITV(N) do { \
  asm volatile("s_waitcnt vmcnt(" #N ")" ::: "memory"); \
  __builtin_amdgcn_sched_barrier(0); } while (0)

#define IS8(r0,r1,r2,r3,r4,r5,r6,r7,p0,p1) do { \
  LOADX4(r0, p0, 0);   LOADX4(r1, p1, 0); \
  LOADX4(r2, p0, 64);  LOADX4(r3, p1, 64); \
  LOADX4(r4, p0, 128); LOADX4(r5, p1, 128); \
  LOADX4(r6, p0, 192); LOADX4(r7, p1, 192); } while (0)

union vv { v4 u; s8 s; };
__device__ __forceinline__ s8 as_s8(v4 x) { vv t; t.u = x; return t.s; }
union uab { u64 q[2]; s8 v; };
union vf4 { v4 u; float f[4]; };

// ---------------- prep kernels ----------------
__global__ void prep_pack(const float* __restrict__ Wih0, const float* __restrict__ Whh0,
                          const float* __restrict__ Wih1, const float* __restrict__ Whh1,
                          const float* __restrict__ Wproj,
                          u16* __restrict__ W0C, u16* __restrict__ WIH1p,
                          u16* __restrict__ WHH0p, u16* __restrict__ WHH1p,
                          u16* __restrict__ Up) {
  int stride = gridDim.x * blockDim.x;
  int i0 = blockIdx.x * blockDim.x + threadIdx.x;
  for (int idx = i0; idx < G4 * 32; idx += stride) {
    int n = idx >> 5, k = idx & 31;
    W0C[idx] = (k < 9) ? (u16)f2bf(Wih0[n * 9 + k]) : (u16)0;
  }
  for (int idx = i0; idx < G4 * 512; idx += stride) {
    int n = idx >> 9, k = idx & 511;
    WIH1p[idx] = (u16)f2bf(Wih1[idx]);
    WHH0p[idx] = (u16)f2bf(Whh0[idx]);
    WHH1p[idx] = (u16)f2bf(Whh1[idx]);
    Up[idx]    = (u16)f2bf(Wih0[n * 9] * Wproj[k]);
  }
}

__global__ void prep_xe(const float* __restrict__ xf, const float* __restrict__ z,
                        const float* __restrict__ Wz, const float* __restrict__ bz,
                        const float* __restrict__ bproj, u16* __restrict__ xe) {
  int idx = blockIdx.x * blockDim.x + threadIdx.x;
  if (idx >= NSTEPS * B_SZ) return;
  int t = idx >> 10, b = idx & 1023;
  float zb[9];
#pragma unroll
  for (int i = 0; i < 9; i++) {
    float s = bz[i];
#pragma unroll
    for (int d = 0; d < 16; d++) s += z[b * 16 + d] * Wz[i * 16 + d];
    zb[i] = s;
  }
  __align__(16) u16 o[16];
  // t>0: prev_y = bpj + Wproj.h1 ; bpj const folded here, Wproj.h1 via U-gemm
  o[0] = (u16)f2bf(zb[0] + (t > 0 ? bproj[0] : 0.f));
#pragma unroll
  for (int e = 0; e < 8; e++) o[1 + e] = (u16)f2bf(xf[b * 512 + t * 8 + e] + zb[1 + e]);
#pragma unroll
  for (int k = 9; k < 16; k++) o[k] = 0;
  uint4* dst = (uint4*)(xe + (size_t)idx * 16);
  dst[0] = *(const uint4*)&o[0];
  dst[1] = *(const uint4*)&o[8];
}

__global__ void prep_state(const float* __restrict__ h0in, u16* __restrict__ h0s,
                           u16* __restrict__ h1s, u32* __restrict__ flags) {
  int i = blockIdx.x * blockDim.x + threadIdx.x;
  if (i < B_SZ * H_SZ) {
    h0s[524288 + i] = (u16)f2bf(h0in[i]);            // slot 1 = initial h0
    h1s[524288 + i] = (u16)f2bf(h0in[524288 + i]);   // slot 1 = initial h1
  }
  if (i < 256) flags[i] = 0;
}

// ---------------- main persistent kernel ----------------
struct MainParams {
  const float* y0; const float* c0;
  const float* bih0; const float* bhh0; const float* bih1; const float* bhh1;
  const float* wproj; const float* bproj;
  const u16* xe; const u16* w0c; const u16* wih1; const u16* whh0;
  const u16* whh1; const u16* up;
  u64* h0u; u64* h1u; float* ypart; u32* flags; float* out;
};

__device__ __forceinline__ f4 MFMA_(s8 a, s8 b, f4 c) {
  return __builtin_amdgcn_mfma_f32_16x16x32_bf16(a, b, c, 0, 0, 0);
}

// prologue-only: K=512 gemm with intrinsic atomic loads (slow, runs once)
__device__ __forceinline__ void gemmK512_2(const u64* hb, int au0, int au1,
    const char* b0p, const char* b1p, f4 acc[4]) {
#pragma unroll
  for (int kc = 0; kc < 16; kc++) {
    uab a0; a0.q[0] = ald(hb + au0 + kc * 8); a0.q[1] = ald(hb + au0 + kc * 8 + 1);
    uab a1; a1.q[0] = ald(hb + au1 + kc * 8); a1.q[1] = ald(hb + au1 + kc * 8 + 1);
    s8 b0 = *(const s8*)(b0p + kc * 64);
    s8 b1 = *(const s8*)(b1p + kc * 64);
    acc[0] = MFMA_(a0.v, b0, acc[0]);
    acc[1] = MFMA_(a0.v, b1, acc[1]);
    acc[2] = MFMA_(a1.v, b0, acc[2]);
    acc[3] = MFMA_(a1.v, b1, acc[3]);
  }
}

// consume 8 regs (4 k-chunks x 2 rows) feeding two acc sets
__device__ __forceinline__ void cons_dual8(
    v4 A0, v4 A1, v4 A2, v4 A3, v4 A4, v4 A5, v4 A6, v4 A7,
    const char* wq0, const char* wq1, const char* wp0, const char* wp1,
    f4 accQ[4], f4 accP[4]) {
#define DPAIR(x, y, OFF) do { \
    s8 bq0 = *(const s8*)(wq0 + OFF); s8 bq1 = *(const s8*)(wq1 + OFF); \
    s8 bp0 = *(const s8*)(wp0 + OFF); s8 bp1 = *(const s8*)(wp1 + OFF); \
    accQ[0] = MFMA_(x, bq0, accQ[0]); accQ[1] = MFMA_(x, bq1, accQ[1]); \
    accQ[2] = MFMA_(y, bq0, accQ[2]); accQ[3] = MFMA_(y, bq1, accQ[3]); \
    accP[0] = MFMA_(x, bp0, accP[0]); accP[1] = MFMA_(x, bp1, accP[1]); \
    accP[2] = MFMA_(y, bp0, accP[2]); accP[3] = MFMA_(y, bp1, accP[3]); } while (0)
  DPAIR(as_s8(A0), as_s8(A1), 0);
  DPAIR(as_s8(A2), as_s8(A3), 64);
  DPAIR(as_s8(A4), as_s8(A5), 128);
  DPAIR(as_s8(A6), as_s8(A7), 192);
#undef DPAIR
}

// arrival: per-wave vmcnt drain -> one relaxed flag store -> 1-wave poll of 64 slots
// -> agent acquire fence (s_waitcnt + buffer_inv): drop stale L2 lines so the
//    following phase's CACHEABLE h loads see the sc1-written data.
__device__ __forceinline__ void barrier_wait(u32* slots, int js, int tid, u32 target) {
  asm volatile("s_waitcnt vmcnt(0)" ::: "memory");
  __syncthreads();
  if (tid == 0) ast32(&slots[js], target);
  if (tid < 64) {
    int spins = 0;
    while (ald32(&slots[tid]) < target) {
      __builtin_amdgcn_s_sleep(1);
      if (++spins > (1 << 18)) break;   // fail-safe: never hang
    }
  }
  __syncthreads();
  __builtin_amdgcn_fence(__ATOMIC_ACQUIRE, "agent");
}

struct LaneCtx { int mb0, grp, pp, jl, hlf; };

// bias, lane^8 gate exchange (i,g <-> f,o), cell math, write h (bf16) to LDS stage
__device__ __forceinline__ void cell_update(f4 acc[4], const float bias[2], float cr[2][2],
    u16* __restrict__ hst, int lbase, const LaneCtx& L, float hval[2][2]) {
#pragma unroll
  for (int m = 0; m < 2; m++)
#pragma unroll
    for (int n = 0; n < 2; n++)
#pragma unroll
      for (int r = 0; r < 4; r++) acc[m * 2 + n][r] += bias[n];
  f4 rx[4];
#pragma unroll
  for (int q = 0; q < 4; q++)
#pragma unroll
    for (int r = 0; r < 4; r++) rx[q][r] = __shfl_xor(acc[q][r], 8);
#pragma unroll
  for (int mtl = 0; mtl < 2; mtl++) {
#pragma unroll
    for (int q = 0; q < 2; q++) {
      int r = L.hlf * 2 + q;
      float iv = L.hlf ? rx[mtl * 2 + 0][r] : acc[mtl * 2 + 0][r];
      float fv = L.hlf ? acc[mtl * 2 + 0][r] : rx[mtl * 2 + 0][r];
      float gv = L.hlf ? rx[mtl * 2 + 1][r] : acc[mtl * 2 + 1][r];
      float ov = L.hlf ? acc[mtl * 2 + 1][r] : rx[mtl * 2 + 1][r];
      float c2 = sigm(fv) * cr[mtl][q] + sigm(iv) * tanh_(gv);
      float hv = sigm(ov) * tanh_(c2);
      cr[mtl][q] = c2;
      hval[mtl][q] = hv;
      int lrow = lbase + mtl * 16 + L.grp * 4 + r;
      hst[lrow * 8 + L.jl] = (u16)f2bf(hv);
    }
  }
}

__global__ __launch_bounds__(512, 2) void lstm_main(MainParams p) {
  extern __shared__ char lds[];
  float* yrow = (float*)(lds + LDS_YROW);
  u16* hst = (u16*)(lds + LDS_HST);

  const int bx = blockIdx.x, chunk = bx >> 6, js = bx & 63;
  const int tid = threadIdx.x, lane = tid & 63, wid = tid >> 6;

  { // stage weight slices into LDS once
    int n = tid & 31, part = tid >> 5;
    int ng = ((n >> 3) << 9) + js * 8 + (n & 7);
#define STAGE(MATP, LOFF) do { \
    const u32* s_ = (const u32*)(p.MATP + (size_t)ng * 512); \
    u32* d_ = (u32*)(lds + LOFF + n * WSTRIDE + part * 64); \
    _Pragma("unroll") for (int q = 0; q < 16; q++) d_[q] = s_[part * 16 + q]; } while (0)
    STAGE(wih1, LDS_WA1);
    STAGE(whh0, LDS_WA0);
    STAGE(whh1, LDS_WB1);
    STAGE(up,   LDS_WBU);
#undef STAGE
    const u32* s0 = (const u32*)(p.w0c + (size_t)ng * 32);
    u32* d0 = (u32*)(lds + LDS_W0C + n * 64);
    d0[part] = s0[part];
    if (tid < 256) yrow[tid] = p.y0[chunk * 256 + tid];
  }

  LaneCtx L;
  L.grp = lane >> 4; L.pp = lane & 15; L.jl = lane & 7; L.hlf = (lane >> 3) & 1;
  L.mb0 = chunk * 256 + wid * 32;
  const int lbase = wid * 32;
  const int j = js * 8 + L.jl;
  const int arow0 = L.mb0 + L.pp, arow1 = L.mb0 + 16 + L.pp;
  const int aoff0 = arow0 * 1024 + L.grp * 16;   // byte offset in [1024][512] bf16
  const int aoff1 = arow1 * 1024 + L.grp * 16;
  const int au0 = arow0 * 128 + L.grp * 2;       // u64 index (prologue)
  const int au1 = arow1 * 128 + L.grp * 2;

  float bias0[2], bias1[2];
#pragma unroll
  for (int ntl = 0; ntl < 2; ntl++) {
    int n = ntl * 16 + L.pp;
    int ng = ((n >> 3) << 9) + js * 8 + (n & 7);
    bias0[ntl] = p.bih0[ng] + p.bhh0[ng];
    bias1[ntl] = p.bih1[ng] + p.bhh1[ng];
  }
  float wpj = p.wproj[j];
  float bpj = p.bproj[0];

  float c0r[2][2], c1r[2][2];
#pragma unroll
  for (int mtl = 0; mtl < 2; mtl++)
#pragma unroll
    for (int q = 0; q < 2; q++) {
      int row = L.mb0 + mtl * 16 + L.grp * 4 + L.hlf * 2 + q;
      c0r[mtl][q] = p.c0[row * 512 + j];
      c1r[mtl][q] = p.c0[524288 + row * 512 + j];
    }

  u32* flagc = p.flags + chunk * 64;
  const char* wA1_0 = lds + LDS_WA1 + L.pp * WSTRIDE + L.grp * 16;
  const char* wA1_1 = lds + LDS_WA1 + (16 + L.pp) * WSTRIDE + L.grp * 16;
  const char* wA0_0 = lds + LDS_WA0 + L.pp * WSTRIDE + L.grp * 16;
  const char* wA0_1 = lds + LDS_WA0 + (16 + L.pp) * WSTRIDE + L.grp * 16;
  const char* wB1_0 = lds + LDS_WB1 + L.pp * WSTRIDE + L.grp * 16;
  const char* wB1_1 = lds + LDS_WB1 + (16 + L.pp) * WSTRIDE + L.grp * 16;
  const char* wBU_0 = lds + LDS_WBU + L.pp * WSTRIDE + L.grp * 16;
  const char* wBU_1 = lds + LDS_WBU + (16 + L.pp) * WSTRIDE + L.grp * 16;
  const char* w0c_0 = lds + LDS_W0C + L.pp * 64 + L.grp * 16;
  const char* w0c_1 = lds + LDS_W0C + (16 + L.pp) * 64 + L.grp * 16;

  const int rot = js & 3;
  const int g0 = ((rot + 0) & 3) * 256, g1 = ((rot + 1) & 3) * 256;
  const int g2 = ((rot + 2) & 3) * 256, g3 = ((rot + 3) & 3) * 256;

  __syncthreads();

  f4 accP[4] = {{0,0,0,0},{0,0,0,0},{0,0,0,0},{0,0,0,0}};   // gates0 accum
  f4 accQ[4] = {{0,0,0,0},{0,0,0,0},{0,0,0,0},{0,0,0,0}};   // gates1 accum

  // ===== prologue: gates0(0) = Whh0 h0(-1) + chunk0(y0) ; carry Whh1 h1(-1) =====
  gemmK512_2(p.h0u + 131072, au0, au1, wA0_0, wA0_1, accP);
  {
    s8 a0 = {0,0,0,0,0,0,0,0}, a1 = {0,0,0,0,0,0,0,0};
    if (L.grp < 2) {
      const char* xb = (const char*)p.xe;   // t = 0
      a0 = *(const s8*)(xb + arow0 * 32 + L.grp * 16);
      a1 = *(const s8*)(xb + arow1 * 32 + L.grp * 16);
      if (L.grp == 0) {
        a0[0] = f2bf(bf2f(a0[0]) + yrow[wid * 32 + L.pp]);
        a1[0] = f2bf(bf2f(a1[0]) + yrow[wid * 32 + 16 + L.pp]);
      }
    }
    s8 b0 = *(const s8*)(w0c_0);
    s8 b1 = *(const s8*)(w0c_1);
    accP[0] = MFMA_(a0, b0, accP[0]);
    accP[1] = MFMA_(a0, b1, accP[1]);
    accP[2] = MFMA_(a1, b0, accP[2]);
    accP[3] = MFMA_(a1, b1, accP[3]);
  }
  {
    float hd[2][2];
    cell_update(accP, bias0, c0r, hst, lbase, L, hd);
  }
  gemmK512_2(p.h1u + 131072, au0, au1, wB1_0, wB1_1, accQ);  // Whh1 h1(-1) carry
  __syncthreads();
  if (tid < 256) {
    const u64* src = (const u64*)&hst[tid * 8];
    u64* dst = p.h0u + (chunk * 256 + tid) * 128 + js * 2;   // slot 0 = h0(0)
    ast(dst, src[0]);
    ast(dst + 1, src[1]);
  }
  barrier_wait(flagc, js, tid, 1u);
#pragma unroll
  for (int q = 0; q < 4; q++) accP[q] = (f4){0, 0, 0, 0};

  v4 A0, A1, A2, A3, A4, A5, A6, A7;
  v4 C0, C1, C2, C3, C4, C5, C6, C7;

  for (int t = 0; t < NSTEPS; t++) {
    // ===== phase A: read h0(t); gates1(t) += Wih1 h0 ; gates0(t+1) += Whh0 h0 =====
    {
      const char* hb = (const char*)p.h0u + (size_t)(t & 1) * 1048576;
      const char* pa0 = hb + aoff0;
      const char* pa1 = hb + aoff1;
      IS8(A0,A1,A2,A3,A4,A5,A6,A7, pa0 + g0, pa1 + g0);
      IS8(C0,C1,C2,C3,C4,C5,C6,C7, pa0 + g1, pa1 + g1);
      WAITV(8);
      cons_dual8(A0,A1,A2,A3,A4,A5,A6,A7, wA1_0+g0, wA1_1+g0, wA0_0+g0, wA0_1+g0, accQ, accP);
      IS8(A0,A1,A2,A3,A4,A5,A6,A7, pa0 + g2, pa1 + g2);
      WAITV(8);
      cons_dual8(C0,C1,C2,C3,C4,C5,C6,C7, wA1_0+g1, wA1_1+g1, wA0_0+g1, wA0_1+g1, accQ, accP);
      IS8(C0,C1,C2,C3,C4,C5,C6,C7, pa0 + g3, pa1 + g3);
      WAITV(8);
      cons_dual8(A0,A1,A2,A3,A4,A5,A6,A7, wA1_0+g2, wA1_1+g2, wA0_0+g2, wA0_1+g2, accQ, accP);
      WAITV(0);
      cons_dual8(C0,C1,C2,C3,C4,C5,C6,C7, wA1_0+g3, wA1_1+g3, wA0_0+g3, wA0_1+g3, accQ, accP);

      float hval[2][2];
      cell_update(accQ, bias1, c1r, hst, lbase, L, hval);
      // proj partials -> ypart[t&1]
#pragma unroll
      for (int mtl = 0; mtl < 2; mtl++)
#pragma unroll
        for (int q = 0; q < 2; q++) {
          float s = hval[mtl][q] * wpj;
          s += __shfl_xor(s, 1);
          s += __shfl_xor(s, 2);
          s += __shfl_xor(s, 4);
          if (L.jl == 0) {
            int row = L.mb0 + mtl * 16 + L.grp * 4 + L.hlf * 2 + q;
            ast32((u32*)&p.ypart[(t & 1) * 65536 + row * 64 + js], __float_as_uint(s));
          }
        }
      __syncthreads();
      if (tid < 256) {
        const u64* src = (const u64*)&hst[tid * 8];
        u64* dst = p.h1u + (size_t)(t & 1) * 131072 + (chunk * 256 + tid) * 128 + js * 2;
        ast(dst, src[0]);
        ast(dst + 1, src[1]);
      }
      barrier_wait(flagc, js, tid, (u32)(2 * t + 2));
#pragma unroll
      for (int q = 0; q < 4; q++) accQ[q] = (f4){0, 0, 0, 0};
    }

    // ===== phase B: read h1(t); gates1(t+1) += Whh1 h1 ; gates0(t+1) += U h1 =====
    {
      const char* hb = (const char*)p.h1u + (size_t)(t & 1) * 1048576;
      const char* pb0 = hb + aoff0;
      const char* pb1 = hb + aoff1;
      IS8(A0,A1,A2,A3,A4,A5,A6,A7, pb0 + g0, pb1 + g0);
      IS8(C0,C1,C2,C3,C4,C5,C6,C7, pb0 + g1, pb1 + g1);
      // distributed y-reduce: wave 0 of every block reduces 4 rows of own chunk.
      // WAITV(0) over-drains wave 0 only; later counted waits become no-ops for it.
      if (tid < 64) {
        int rloc = (tid >> 4) * 64 + js;
        const char* yq = (const char*)(p.ypart + (size_t)(t & 1) * 65536
                       + (size_t)(chunk * 256 + rloc) * 64 + (size_t)(tid & 15) * 4);
        v4 Yv;
        LOADX4(Yv, yq, 0);
        WAITV(0);
        vf4 w; w.u = Yv;
        float s = (w.f[0] + w.f[1]) + (w.f[2] + w.f[3]);
        s += __shfl_xor(s, 1);
        s += __shfl_xor(s, 2);
        s += __shfl_xor(s, 4);
        s += __shfl_xor(s, 8);
        if ((tid & 15) == 0) p.out[(chunk * 256 + rloc) * 64 + t] = s + bpj;
      }
      WAITV(8);
      cons_dual8(A0,A1,A2,A3,A4,A5,A6,A7, wB1_0+g0, wB1_1+g0, wBU_0+g0, wBU_1+g0, accQ, accP);
      IS8(A0,A1,A2,A3,A4,A5,A6,A7, pb0 + g2, pb1 + g2);
      WAITV(8);
      cons_dual8(C0,C1,C2,C3,C4,C5,C6,C7, wB1_0+g1, wB1_1+g1, wBU_0+g1, wBU_1+g1, accQ, accP);
      IS8(C0,C1,C2,C3,C4,C5,C6,C7, pb0 + g3, pb1 + g3);
      WAITV(8);
      cons_dual8(A0,A1,A2,A3,A4,A5,A6,A7, wB1_0+g2, wB1_1+g2, wBU_0+g2, wBU_1+g2, accQ, accP);
      WAITV(0);
      cons_dual8(C0,C1,C2,C3,C4,C5,C6,C7, wB1_0+g3, wB1_1+g3, wBU_0+g3, wBU_1+g3, accQ, accP);

      // chunk0 of gates0(t+1): exo+z(+bproj) const part (y folded into U + xe slot0)
      {
        int tn = (t < 63) ? t + 1 : 63;
        s8 a0 = {0,0,0,0,0,0,0,0}, a1 = {0,0,0,0,0,0,0,0};
        if (L.grp < 2) {
          const char* xb = (const char*)p.xe + (size_t)tn * 32768;
          a0 = *(const s8*)(xb + arow0 * 32 + L.grp * 16);
          a1 = *(const s8*)(xb + arow1 * 32 + L.grp * 16);
        }
        s8 b0 = *(const s8*)(w0c_0);
        s8 b1 = *(const s8*)(w0c_1);
        accP[0] = MFMA_(a0, b0, accP[0]);
        accP[1] = MFMA_(a0, b1, accP[1]);
        accP[2] = MFMA_(a1, b0, accP[2]);
        accP[3] = MFMA_(a1, b1, accP[3]);
      }
      float hd[2][2];
      cell_update(accP, bias0, c0r, hst, lbase, L, hd);
      __syncthreads();
      if (tid < 256) {
        const u64* src = (const u64*)&hst[tid * 8];
        u64* dst = p.h0u + (size_t)((t + 1) & 1) * 131072 + (chunk * 256 + tid) * 128 + js * 2;
        ast(dst, src[0]);
        ast(dst + 1, src[1]);
      }
      barrier_wait(flagc, js, tid, (u32)(2 * t + 3));
#pragma unroll
      for (int q = 0; q < 4; q++) accP[q] = (f4){0, 0, 0, 0};
    }
  }
}

extern "C" void kernel_launch(void* const* d_in, const int* in_sizes, int n_in,
                              void* d_out, int out_size, void* d_ws, size_t ws_size,
                              hipStream_t stream) {
  const float* y0   = (const float*)d_in[0];
  const float* xf   = (const float*)d_in[1];
  const float* h0   = (const float*)d_in[2];
  const float* c0   = (const float*)d_in[3];
  const float* z    = (const float*)d_in[4];
  const float* Wih0 = (const float*)d_in[5];
  const float* Whh0 = (const float*)d_in[6];
  const float* bih0 = (const float*)d_in[7];
  const float* bhh0 = (const float*)d_in[8];
  const float* Wih1 = (const float*)d_in[9];
  const float* Whh1 = (const float*)d_in[10];
  const float* bih1 = (const float*)d_in[11];
  const float* bhh1 = (const float*)d_in[12];
  const float* Wpr  = (const float*)d_in[13];
  const float* bpr  = (const float*)d_in[14];
  const float* Wz   = (const float*)d_in[15];
  const float* bz   = (const float*)d_in[16];

  if (ws_size < WS_NEEDED) return;
  char* ws = (char*)d_ws;
  u16* xe    = (u16*)(ws + WS_XE);
  u16* w0c   = (u16*)(ws + WS_W0C);
  u16* wih1  = (u16*)(ws + WS_WIH1);
  u16* whh0  = (u16*)(ws + WS_WHH0);
  u16* whh1  = (u16*)(ws + WS_WHH1);
  u16* up    = (u16*)(ws + WS_UP);
  u64* h0u   = (u64*)(ws + WS_H0S);
  u64* h1u   = (u64*)(ws + WS_H1S);
  float* ypart = (float*)(ws + WS_YPART);
  u32* flags = (u32*)(ws + WS_FLAGS);

  prep_pack<<<1024, 256, 0, stream>>>(Wih0, Whh0, Wih1, Whh1, Wpr,
                                      w0c, wih1, whh0, whh1, up);
  prep_xe<<<256, 256, 0, stream>>>(xf, z, Wz, bz, bpr, xe);
  prep_state<<<2048, 256, 0, stream>>>(h0, (u16*)h0u, (u16*)h1u, flags);

  MainParams prm;
  prm.y0 = y0; prm.c0 = c0;
  prm.bih0 = bih0; prm.bhh0 = bhh0; prm.bih1 = bih1; prm.bhh1 = bhh1;
  prm.wproj = Wpr; prm.bproj = bpr;
  prm.xe = xe; prm.w0c = w0c; prm.wih1 = wih1; prm.whh0 = whh0;
  prm.whh1 = whh1; prm.up = up;
  prm.h0u = h0u; prm.h1u = h1u; prm.ypart = ypart; prm.flags = flags;
  prm.out = (float*)d_out;

  hipFuncSetAttribute((const void*)lstm_main, hipFuncAttributeMaxDynamicSharedMemorySize, LDS_TOTAL);
  void* args[] = { &prm };
  hipLaunchCooperativeKernel((void*)lstm_main, dim3(256), dim3(512), args, LDS_TOTAL, stream);
}

// Round 8
// 1475.290 us; speedup vs baseline: 2.1949x; 2.1949x over previous
//
#include <hip/hip_runtime.h>

typedef unsigned int u32;
typedef unsigned short u16;
typedef unsigned long long u64;
typedef short s8 __attribute__((ext_vector_type(8)));   // 8 x bf16 (as i16)
typedef float f4 __attribute__((ext_vector_type(4)));
typedef u32 v4 __attribute__((ext_vector_type(4)));     // 16B asm load payload

#define B_SZ   1024
#define H_SZ   512
#define G4     2048
#define NSTEPS 64

// ws layout (bytes)
#define WS_XE     0u          // [64][1024][16] bf16  = 2097152
#define WS_W0C    2097152u    // [2048][32]  bf16     = 131072
#define WS_WIH1   2228224u    // [2048][512] bf16     = 2097152
#define WS_WHH0   4325376u    // [2048][512] bf16     = 2097152
#define WS_WHH1   6422528u    // [2048][512] bf16     = 2097152
#define WS_UP     8519680u    // [2048][512] bf16     = 2097152  (U = wih0[:,0] x wproj)
#define WS_H0S    10616832u   // [2][TILED 1024x512] bf16 = 2097152
#define WS_H1S    12713984u   // [2][TILED 1024x512] bf16 = 2097152
#define WS_YPART  14811136u   // [2][1024][64] f32    = 524288
#define WS_FLAGS  15335424u   // [4][64] u32          = 1024
#define WS_NEEDED 15336448u

// h TILED layout: tile(rblk=r>>4, kblk=k>>5) = 1KB at rblk*16384 + kblk*1024;
// inner byte = lane*16, lane = (r&15) + ((k>>3)&3)*16  == MFMA A-frag mapping.

// LDS layout (bytes); weight row stride 1040 (520 bf16: 2-way bank alias = free)
#define WSTRIDE   1040
#define LDS_WA1   0        // W_ih1 slice  32 x 1040
#define LDS_WA0   33280    // W_hh0 slice
#define LDS_WB1   66560    // W_hh1 slice
#define LDS_WBU   99840    // U slice
#define LDS_W0C   133120   // chunk0 weights 32 x 64B
#define LDS_YROW  135168   // f32[256]
#define LDS_HST   136192   // u16[256][8]
#define LDS_TOTAL 140288

__device__ __forceinline__ float bf2f(short s) {
  u32 u = ((u32)(u16)s) << 16; float f; __builtin_memcpy(&f, &u, 4); return f;
}
__device__ __forceinline__ short f2bf(float f) {
  u32 u; __builtin_memcpy(&u, &f, 4);
  u = (u + 0x7fffu + ((u >> 16) & 1u)) >> 16; return (short)u;
}
__device__ __forceinline__ float sigm(float x) { return 1.f / (1.f + __expf(-x)); }
__device__ __forceinline__ float tanh_(float x) {
  float ax = fminf(fabsf(x), 15.f);
  float e = __expf(2.f * ax);
  float r = (e - 1.f) / (e + 1.f);
  return x < 0.f ? -r : r;
}

__device__ __forceinline__ u64 ald(const u64* p) {
  return __hip_atomic_load(p, __ATOMIC_RELAXED, __HIP_MEMORY_SCOPE_AGENT);
}
__device__ __forceinline__ void ast(u64* p, u64 v) {
  __hip_atomic_store(p, v, __ATOMIC_RELAXED, __HIP_MEMORY_SCOPE_AGENT);
}
__device__ __forceinline__ u32 ald32(const u32* p) {
  return __hip_atomic_load(p, __ATOMIC_RELAXED, __HIP_MEMORY_SCOPE_AGENT);
}
__device__ __forceinline__ void ast32(u32* p, u32 v) {
  __hip_atomic_store(p, v, __ATOMIC_RELAXED, __HIP_MEMORY_SCOPE_AGENT);
}

// device-scope 16B load (sc1: L2-bypass, L3-coherent); async until WAITV
#define LOADX4(dst, ptr, IMM) \
  asm volatile("global_load_dwordx4 %0, %1, off offset:" #IMM " sc1" : "=v"(dst) : "v"(ptr))
#define WAITV(N) do { \
  asm volatile("s_waitcnt vmcnt(" #N ")" ::: "memory"); \
  __builtin_amdgcn_sched_barrier(0); } while (0)

// one k-group = 4 tiles (4 k-chunks x 1KB), two row-blocks; lane-contiguous
#define IS8(r0,r1,r2,r3,r4,r5,r6,r7,p0,p1) do { \
  LOADX4(r0, p0, 0);    LOADX4(r1, p1, 0); \
  LOADX4(r2, p0, 1024); LOADX4(r3, p1, 1024); \
  LOADX4(r4, p0, 2048); LOADX4(r5, p1, 2048); \
  LOADX4(r6, p0, 3072); LOADX4(r7, p1, 3072); } while (0)

union vv { v4 u; s8 s; };
__device__ __forceinline__ s8 as_s8(v4 x) { vv t; t.u = x; return t.s; }
union uab { u64 q[2]; s8 v; };
union vf4 { v4 u; float f[4]; };

// ---------------- prep kernels ----------------
__global__ void prep_pack(const float* __restrict__ Wih0, const float* __restrict__ Whh0,
                          const float* __restrict__ Wih1, const float* __restrict__ Whh1,
                          const float* __restrict__ Wproj,
                          u16* __restrict__ W0C, u16* __restrict__ WIH1p,
                          u16* __restrict__ WHH0p, u16* __restrict__ WHH1p,
                          u16* __restrict__ Up) {
  int stride = gridDim.x * blockDim.x;
  int i0 = blockIdx.x * blockDim.x + threadIdx.x;
  for (int idx = i0; idx < G4 * 32; idx += stride) {
    int n = idx >> 5, k = idx & 31;
    W0C[idx] = (k < 9) ? (u16)f2bf(Wih0[n * 9 + k]) : (u16)0;
  }
  for (int idx = i0; idx < G4 * 512; idx += stride) {
    int n = idx >> 9, k = idx & 511;
    WIH1p[idx] = (u16)f2bf(Wih1[idx]);
    WHH0p[idx] = (u16)f2bf(Whh0[idx]);
    WHH1p[idx] = (u16)f2bf(Whh1[idx]);
    Up[idx]    = (u16)f2bf(Wih0[n * 9] * Wproj[k]);
  }
}

__global__ void prep_xe(const float* __restrict__ xf, const float* __restrict__ z,
                        const float* __restrict__ Wz, const float* __restrict__ bz,
                        const float* __restrict__ bproj, u16* __restrict__ xe) {
  int idx = blockIdx.x * blockDim.x + threadIdx.x;
  if (idx >= NSTEPS * B_SZ) return;
  int t = idx >> 10, b = idx & 1023;
  float zb[9];
#pragma unroll
  for (int i = 0; i < 9; i++) {
    float s = bz[i];
#pragma unroll
    for (int d = 0; d < 16; d++) s += z[b * 16 + d] * Wz[i * 16 + d];
    zb[i] = s;
  }
  __align__(16) u16 o[16];
  // t>0: prev_y = bpj + Wproj.h1 ; bpj const folded here, Wproj.h1 via U-gemm
  o[0] = (u16)f2bf(zb[0] + (t > 0 ? bproj[0] : 0.f));
#pragma unroll
  for (int e = 0; e < 8; e++) o[1 + e] = (u16)f2bf(xf[b * 512 + t * 8 + e] + zb[1 + e]);
#pragma unroll
  for (int k = 9; k < 16; k++) o[k] = 0;
  uint4* dst = (uint4*)(xe + (size_t)idx * 16);
  dst[0] = *(const uint4*)&o[0];
  dst[1] = *(const uint4*)&o[8];
}

// initial h -> TILED layout, slot 1
__global__ void prep_state(const float* __restrict__ h0in, u16* __restrict__ h0s,
                           u16* __restrict__ h1s, u32* __restrict__ flags) {
  int i = blockIdx.x * blockDim.x + threadIdx.x;
  if (i < B_SZ * H_SZ) {
    int r = i >> 9, k = i & 511;
    int ti = ((r >> 4) * 16 + (k >> 5)) * 512
           + ((r & 15) + (((k >> 3) & 3) << 4)) * 8 + (k & 7);
    h0s[524288 + ti] = (u16)f2bf(h0in[i]);
    h1s[524288 + ti] = (u16)f2bf(h0in[524288 + i]);
  }
  if (i < 256) flags[i] = 0;
}

// ---------------- main persistent kernel ----------------
struct MainParams {
  const float* y0; const float* c0;
  const float* bih0; const float* bhh0; const float* bih1; const float* bhh1;
  const float* wproj; const float* bproj;
  const u16* xe; const u16* w0c; const u16* wih1; const u16* whh0;
  const u16* whh1; const u16* up;
  u64* h0u; u64* h1u; float* ypart; u32* flags; float* out;
};

__device__ __forceinline__ f4 MFMA_(s8 a, s8 b, f4 c) {
  return __builtin_amdgcn_mfma_f32_16x16x32_bf16(a, b, c, 0, 0, 0);
}

// prologue-only: K=512 gemm, TILED h, intrinsic atomic loads (slow, runs once)
// tb0/tb1: u64 index of this lane's slot in row-block tiles (+kc*128 per chunk)
__device__ __forceinline__ void gemmK512_2(const u64* hb, int tb0, int tb1,
    const char* b0p, const char* b1p, f4 acc[4]) {
#pragma unroll
  for (int kc = 0; kc < 16; kc++) {
    uab a0; a0.q[0] = ald(hb + tb0 + kc * 128); a0.q[1] = ald(hb + tb0 + kc * 128 + 1);
    uab a1; a1.q[0] = ald(hb + tb1 + kc * 128); a1.q[1] = ald(hb + tb1 + kc * 128 + 1);
    s8 b0 = *(const s8*)(b0p + kc * 64);
    s8 b1 = *(const s8*)(b1p + kc * 64);
    acc[0] = MFMA_(a0.v, b0, acc[0]);
    acc[1] = MFMA_(a0.v, b1, acc[1]);
    acc[2] = MFMA_(a1.v, b0, acc[2]);
    acc[3] = MFMA_(a1.v, b1, acc[3]);
  }
}

// consume 8 regs (4 k-chunks x 2 row-blocks) feeding two acc sets
__device__ __forceinline__ void cons_dual8(
    v4 A0, v4 A1, v4 A2, v4 A3, v4 A4, v4 A5, v4 A6, v4 A7,
    const char* wq0, const char* wq1, const char* wp0, const char* wp1,
    f4 accQ[4], f4 accP[4]) {
#define DPAIR(x, y, OFF) do { \
    s8 bq0 = *(const s8*)(wq0 + OFF); s8 bq1 = *(const s8*)(wq1 + OFF); \
    s8 bp0 = *(const s8*)(wp0 + OFF); s8 bp1 = *(const s8*)(wp1 + OFF); \
    accQ[0] = MFMA_(x, bq0, accQ[0]); accQ[1] = MFMA_(x, bq1, accQ[1]); \
    accQ[2] = MFMA_(y, bq0, accQ[2]); accQ[3] = MFMA_(y, bq1, accQ[3]); \
    accP[0] = MFMA_(x, bp0, accP[0]); accP[1] = MFMA_(x, bp1, accP[1]); \
    accP[2] = MFMA_(y, bp0, accP[2]); accP[3] = MFMA_(y, bp1, accP[3]); } while (0)
  DPAIR(as_s8(A0), as_s8(A1), 0);
  DPAIR(as_s8(A2), as_s8(A3), 64);
  DPAIR(as_s8(A4), as_s8(A5), 128);
  DPAIR(as_s8(A6), as_s8(A7), 192);
#undef DPAIR
}

// arrival: per-wave vmcnt drain -> one relaxed flag store -> 1-wave poll of 64 slots
__device__ __forceinline__ void barrier_wait(u32* slots, int js, int tid, u32 target) {
  asm volatile("s_waitcnt vmcnt(0)" ::: "memory");
  __syncthreads();
  if (tid == 0) ast32(&slots[js], target);
  if (tid < 64) {
    int spins = 0;
    while (ald32(&slots[tid]) < target) {
      __builtin_amdgcn_s_sleep(1);
      if (++spins > (1 << 18)) break;   // fail-safe: never hang
    }
  }
  __syncthreads();
}

struct LaneCtx { int mb0, grp, pp, jl, hlf; };

// bias, lane^8 gate exchange (i,g <-> f,o), cell math, write h (bf16) to LDS stage
__device__ __forceinline__ void cell_update(f4 acc[4], const float bias[2], float cr[2][2],
    u16* __restrict__ hst, int lbase, const LaneCtx& L, float hval[2][2]) {
#pragma unroll
  for (int m = 0; m < 2; m++)
#pragma unroll
    for (int n = 0; n < 2; n++)
#pragma unroll
      for (int r = 0; r < 4; r++) acc[m * 2 + n][r] += bias[n];
  f4 rx[4];
#pragma unroll
  for (int q = 0; q < 4; q++)
#pragma unroll
    for (int r = 0; r < 4; r++) rx[q][r] = __shfl_xor(acc[q][r], 8);
#pragma unroll
  for (int mtl = 0; mtl < 2; mtl++) {
#pragma unroll
    for (int q = 0; q < 2; q++) {
      int r = L.hlf * 2 + q;
      float iv = L.hlf ? rx[mtl * 2 + 0][r] : acc[mtl * 2 + 0][r];
      float fv = L.hlf ? acc[mtl * 2 + 0][r] : rx[mtl * 2 + 0][r];
      float gv = L.hlf ? rx[mtl * 2 + 1][r] : acc[mtl * 2 + 1][r];
      float ov = L.hlf ? acc[mtl * 2 + 1][r] : rx[mtl * 2 + 1][r];
      float c2 = sigm(fv) * cr[mtl][q] + sigm(iv) * tanh_(gv);
      float hv = sigm(ov) * tanh_(c2);
      cr[mtl][q] = c2;
      hval[mtl][q] = hv;
      int lrow = lbase + mtl * 16 + L.grp * 4 + r;
      hst[lrow * 8 + L.jl] = (u16)f2bf(hv);
    }
  }
}

__global__ __launch_bounds__(512, 2) void lstm_main(MainParams p) {
  extern __shared__ char lds[];
  float* yrow = (float*)(lds + LDS_YROW);
  u16* hst = (u16*)(lds + LDS_HST);

  const int bx = blockIdx.x, chunk = bx >> 6, js = bx & 63;
  const int tid = threadIdx.x, lane = tid & 63, wid = tid >> 6;

  { // stage weight slices into LDS once
    int n = tid & 31, part = tid >> 5;
    int ng = ((n >> 3) << 9) + js * 8 + (n & 7);
#define STAGE(MATP, LOFF) do { \
    const u32* s_ = (const u32*)(p.MATP + (size_t)ng * 512); \
    u32* d_ = (u32*)(lds + LOFF + n * WSTRIDE + part * 64); \
    _Pragma("unroll") for (int q = 0; q < 16; q++) d_[q] = s_[part * 16 + q]; } while (0)
    STAGE(wih1, LDS_WA1);
    STAGE(whh0, LDS_WA0);
    STAGE(whh1, LDS_WB1);
    STAGE(up,   LDS_WBU);
#undef STAGE
    const u32* s0 = (const u32*)(p.w0c + (size_t)ng * 32);
    u32* d0 = (u32*)(lds + LDS_W0C + n * 64);
    d0[part] = s0[part];
    if (tid < 256) yrow[tid] = p.y0[chunk * 256 + tid];
  }

  LaneCtx L;
  L.grp = lane >> 4; L.pp = lane & 15; L.jl = lane & 7; L.hlf = (lane >> 3) & 1;
  L.mb0 = chunk * 256 + wid * 32;
  const int lbase = wid * 32;
  const int j = js * 8 + L.jl;
  const int rb0 = chunk * 16 + wid * 2;              // row-block of arow0 set
  const int aoff0 = rb0 * 16384 + lane * 16;         // TILED byte offset
  const int aoff1 = aoff0 + 16384;                   // next row-block
  const int tb0 = rb0 * 2048 + lane * 2;             // u64 idx (prologue)
  const int tb1 = tb0 + 2048;
  // producer store slot (tid<256): row r = chunk*256+tid
  const int pst = (chunk * 16 + (tid >> 4)) * 2048 + (js >> 2) * 128
                + ((tid & 15) + ((js & 3) << 4)) * 2;

  float bias0[2], bias1[2];
#pragma unroll
  for (int ntl = 0; ntl < 2; ntl++) {
    int n = ntl * 16 + L.pp;
    int ng = ((n >> 3) << 9) + js * 8 + (n & 7);
    bias0[ntl] = p.bih0[ng] + p.bhh0[ng];
    bias1[ntl] = p.bih1[ng] + p.bhh1[ng];
  }
  float wpj = p.wproj[j];
  float bpj = p.bproj[0];

  float c0r[2][2], c1r[2][2];
#pragma unroll
  for (int mtl = 0; mtl < 2; mtl++)
#pragma unroll
    for (int q = 0; q < 2; q++) {
      int row = L.mb0 + mtl * 16 + L.grp * 4 + L.hlf * 2 + q;
      c0r[mtl][q] = p.c0[row * 512 + j];
      c1r[mtl][q] = p.c0[524288 + row * 512 + j];
    }

  u32* flagc = p.flags + chunk * 64;
  const char* wA1_0 = lds + LDS_WA1 + L.pp * WSTRIDE + L.grp * 16;
  const char* wA1_1 = lds + LDS_WA1 + (16 + L.pp) * WSTRIDE + L.grp * 16;
  const char* wA0_0 = lds + LDS_WA0 + L.pp * WSTRIDE + L.grp * 16;
  const char* wA0_1 = lds + LDS_WA0 + (16 + L.pp) * WSTRIDE + L.grp * 16;
  const char* wB1_0 = lds + LDS_WB1 + L.pp * WSTRIDE + L.grp * 16;
  const char* wB1_1 = lds + LDS_WB1 + (16 + L.pp) * WSTRIDE + L.grp * 16;
  const char* wBU_0 = lds + LDS_WBU + L.pp * WSTRIDE + L.grp * 16;
  const char* wBU_1 = lds + LDS_WBU + (16 + L.pp) * WSTRIDE + L.grp * 16;
  const char* w0c_0 = lds + LDS_W0C + L.pp * 64 + L.grp * 16;
  const char* w0c_1 = lds + LDS_W0C + (16 + L.pp) * 64 + L.grp * 16;

  const int rot = js & 3;
  const int g0 = ((rot + 0) & 3) * 4096, g1 = ((rot + 1) & 3) * 4096;
  const int g2 = ((rot + 2) & 3) * 4096, g3 = ((rot + 3) & 3) * 4096;
  // weight byte offset per k-group = (g/4096)*256
  const int h0 = g0 >> 4, h1 = g1 >> 4, h2 = g2 >> 4, h3 = g3 >> 4;

  __syncthreads();

  f4 accP[4] = {{0,0,0,0},{0,0,0,0},{0,0,0,0},{0,0,0,0}};   // gates0 accum
  f4 accQ[4] = {{0,0,0,0},{0,0,0,0},{0,0,0,0},{0,0,0,0}};   // gates1 accum

  // ===== prologue: gates0(0) = Whh0 h0(-1) + chunk0(y0) ; carry Whh1 h1(-1) =====
  gemmK512_2(p.h0u + 131072, tb0, tb1, wA0_0, wA0_1, accP);
  {
    s8 a0 = {0,0,0,0,0,0,0,0}, a1 = {0,0,0,0,0,0,0,0};
    if (L.grp < 2) {
      const char* xb = (const char*)p.xe;   // t = 0
      a0 = *(const s8*)(xb + (L.mb0 + L.pp) * 32 + L.grp * 16);
      a1 = *(const s8*)(xb + (L.mb0 + 16 + L.pp) * 32 + L.grp * 16);
      if (L.grp == 0) {
        a0[0] = f2bf(bf2f(a0[0]) + yrow[wid * 32 + L.pp]);
        a1[0] = f2bf(bf2f(a1[0]) + yrow[wid * 32 + 16 + L.pp]);
      }
    }
    s8 b0 = *(const s8*)(w0c_0);
    s8 b1 = *(const s8*)(w0c_1);
    accP[0] = MFMA_(a0, b0, accP[0]);
    accP[1] = MFMA_(a0, b1, accP[1]);
    accP[2] = MFMA_(a1, b0, accP[2]);
    accP[3] = MFMA_(a1, b1, accP[3]);
  }
  {
    float hd[2][2];
    cell_update(accP, bias0, c0r, hst, lbase, L, hd);
  }
  gemmK512_2(p.h1u + 131072, tb0, tb1, wB1_0, wB1_1, accQ);  // Whh1 h1(-1) carry
  __syncthreads();
  if (tid < 256) {
    const u64* src = (const u64*)&hst[tid * 8];
    u64* dst = p.h0u + pst;   // slot 0 = h0(0)
    ast(dst, src[0]);
    ast(dst + 1, src[1]);
  }
  barrier_wait(flagc, js, tid, 1u);
#pragma unroll
  for (int q = 0; q < 4; q++) accP[q] = (f4){0, 0, 0, 0};

  v4 A0, A1, A2, A3, A4, A5, A6, A7;
  v4 C0, C1, C2, C3, C4, C5, C6, C7;

  for (int t = 0; t < NSTEPS; t++) {
    // ===== phase A: read h0(t); gates1(t) += Wih1 h0 ; gates0(t+1) += Whh0 h0 =====
    {
      const char* hb = (const char*)p.h0u + (size_t)(t & 1) * 1048576;
      const char* pa0 = hb + aoff0;
      const char* pa1 = hb + aoff1;
      IS8(A0,A1,A2,A3,A4,A5,A6,A7, pa0 + g0, pa1 + g0);
      IS8(C0,C1,C2,C3,C4,C5,C6,C7, pa0 + g1, pa1 + g1);
      WAITV(8);
      cons_dual8(A0,A1,A2,A3,A4,A5,A6,A7, wA1_0+h0, wA1_1+h0, wA0_0+h0, wA0_1+h0, accQ, accP);
      IS8(A0,A1,A2,A3,A4,A5,A6,A7, pa0 + g2, pa1 + g2);
      WAITV(8);
      cons_dual8(C0,C1,C2,C3,C4,C5,C6,C7, wA1_0+h1, wA1_1+h1, wA0_0+h1, wA0_1+h1, accQ, accP);
      IS8(C0,C1,C2,C3,C4,C5,C6,C7, pa0 + g3, pa1 + g3);
      WAITV(8);
      cons_dual8(A0,A1,A2,A3,A4,A5,A6,A7, wA1_0+h2, wA1_1+h2, wA0_0+h2, wA0_1+h2, accQ, accP);
      WAITV(0);
      cons_dual8(C0,C1,C2,C3,C4,C5,C6,C7, wA1_0+h3, wA1_1+h3, wA0_0+h3, wA0_1+h3, accQ, accP);

      float hval[2][2];
      cell_update(accQ, bias1, c1r, hst, lbase, L, hval);
      // proj partials -> ypart[t&1]
#pragma unroll
      for (int mtl = 0; mtl < 2; mtl++)
#pragma unroll
        for (int q = 0; q < 2; q++) {
          float s = hval[mtl][q] * wpj;
          s += __shfl_xor(s, 1);
          s += __shfl_xor(s, 2);
          s += __shfl_xor(s, 4);
          if (L.jl == 0) {
            int row = L.mb0 + mtl * 16 + L.grp * 4 + L.hlf * 2 + q;
            ast32((u32*)&p.ypart[(t & 1) * 65536 + row * 64 + js], __float_as_uint(s));
          }
        }
      __syncthreads();
      if (tid < 256) {
        const u64* src = (const u64*)&hst[tid * 8];
        u64* dst = p.h1u + (size_t)(t & 1) * 131072 + pst;
        ast(dst, src[0]);
        ast(dst + 1, src[1]);
      }
      barrier_wait(flagc, js, tid, (u32)(2 * t + 2));
#pragma unroll
      for (int q = 0; q < 4; q++) accQ[q] = (f4){0, 0, 0, 0};
    }

    // ===== phase B: read h1(t); gates1(t+1) += Whh1 h1 ; gates0(t+1) += U h1 =====
    {
      const char* hb = (const char*)p.h1u + (size_t)(t & 1) * 1048576;
      const char* pb0 = hb + aoff0;
      const char* pb1 = hb + aoff1;
      IS8(A0,A1,A2,A3,A4,A5,A6,A7, pb0 + g0, pb1 + g0);
      IS8(C0,C1,C2,C3,C4,C5,C6,C7, pb0 + g1, pb1 + g1);
      // distributed y-reduce: wave 0 of every block reduces 4 rows of own chunk.
      // WAITV(0) over-drains wave 0 only; later counted waits become no-ops for it.
      if (tid < 64) {
        int rloc = (tid >> 4) * 64 + js;
        const char* yq = (const char*)(p.ypart + (size_t)(t & 1) * 65536
                       + (size_t)(chunk * 256 + rloc) * 64 + (size_t)(tid & 15) * 4);
        v4 Yv;
        LOADX4(Yv, yq, 0);
        WAITV(0);
        vf4 w; w.u = Yv;
        float s = (w.f[0] + w.f[1]) + (w.f[2] + w.f[3]);
        s += __shfl_xor(s, 1);
        s += __shfl_xor(s, 2);
        s += __shfl_xor(s, 4);
        s += __shfl_xor(s, 8);
        if ((tid & 15) == 0) p.out[(chunk * 256 + rloc) * 64 + t] = s + bpj;
      }
      WAITV(8);
      cons_dual8(A0,A1,A2,A3,A4,A5,A6,A7, wB1_0+h0, wB1_1+h0, wBU_0+h0, wBU_1+h0, accQ, accP);
      IS8(A0,A1,A2,A3,A4,A5,A6,A7, pb0 + g2, pb1 + g2);
      WAITV(8);
      cons_dual8(C0,C1,C2,C3,C4,C5,C6,C7, wB1_0+h1, wB1_1+h1, wBU_0+h1, wBU_1+h1, accQ, accP);
      IS8(C0,C1,C2,C3,C4,C5,C6,C7, pb0 + g3, pb1 + g3);
      WAITV(8);
      cons_dual8(A0,A1,A2,A3,A4,A5,A6,A7, wB1_0+h2, wB1_1+h2, wBU_0+h2, wBU_1+h2, accQ, accP);
      WAITV(0);
      cons_dual8(C0,C1,C2,C3,C4,C5,C6,C7, wB1_0+h3, wB1_1+h3, wBU_0+h3, wBU_1+h3, accQ, accP);

      // chunk0 of gates0(t+1): exo+z(+bproj) const part (y folded into U + xe slot0)
      {
        int tn = (t < 63) ? t + 1 : 63;
        s8 a0 = {0,0,0,0,0,0,0,0}, a1 = {0,0,0,0,0,0,0,0};
        if (L.grp < 2) {
          const char* xb = (const char*)p.xe + (size_t)tn * 32768;
          a0 = *(const s8*)(xb + (L.mb0 + L.pp) * 32 + L.grp * 16);
          a1 = *(const s8*)(xb + (L.mb0 + 16 + L.pp) * 32 + L.grp * 16);
        }
        s8 b0 = *(const s8*)(w0c_0);
        s8 b1 = *(const s8*)(w0c_1);
        accP[0] = MFMA_(a0, b0, accP[0]);
        accP[1] = MFMA_(a0, b1, accP[1]);
        accP[2] = MFMA_(a1, b0, accP[2]);
        accP[3] = MFMA_(a1, b1, accP[3]);
      }
      float hd[2][2];
      cell_update(accP, bias0, c0r, hst, lbase, L, hd);
      __syncthreads();
      if (tid < 256) {
        const u64* src = (const u64*)&hst[tid * 8];
        u64* dst = p.h0u + (size_t)((t + 1) & 1) * 131072 + pst;
        ast(dst, src[0]);
        ast(dst + 1, src[1]);
      }
      barrier_wait(flagc, js, tid, (u32)(2 * t + 3));
#pragma unroll
      for (int q = 0; q < 4; q++) accP[q] = (f4){0, 0, 0, 0};
    }
  }
}

extern "C" void kernel_launch(void* const* d_in, const int* in_sizes, int n_in,
                              void* d_out, int out_size, void* d_ws, size_t ws_size,
                              hipStream_t stream) {
  const float* y0   = (const float*)d_in[0];
  const float* xf   = (const float*)d_in[1];
  const float* h0   = (const float*)d_in[2];
  const float* c0   = (const float*)d_in[3];
  const float* z    = (const float*)d_in[4];
  const float* Wih0 = (const float*)d_in[5];
  const float* Whh0 = (const float*)d_in[6];
  const float* bih0 = (const float*)d_in[7];
  const float* bhh0 = (const float*)d_in[8];
  const float* Wih1 = (const float*)d_in[9];
  const float* Whh1 = (const float*)d_in[10];
  const float* bih1 = (const float*)d_in[11];
  const float* bhh1 = (const float*)d_in[12];
  const float* Wpr  = (const float*)d_in[13];
  const float* bpr  = (const float*)d_in[14];
  const float* Wz   = (const float*)d_in[15];
  const float* bz   = (const float*)d_in[16];

  if (ws_size < WS_NEEDED) return;
  char* ws = (char*)d_ws;
  u16* xe    = (u16*)(ws + WS_XE);
  u16* w0c   = (u16*)(ws + WS_W0C);
  u16* wih1  = (u16*)(ws + WS_WIH1);
  u16* whh0  = (u16*)(ws + WS_WHH0);
  u16* whh1  = (u16*)(ws + WS_WHH1);
  u16* up    = (u16*)(ws + WS_UP);
  u64* h0u   = (u64*)(ws + WS_H0S);
  u64* h1u   = (u64*)(ws + WS_H1S);
  float* ypart = (float*)(ws + WS_YPART);
  u32* flags = (u32*)(ws + WS_FLAGS);

  prep_pack<<<1024, 256, 0, stream>>>(Wih0, Whh0, Wih1, Whh1, Wpr,
                                      w0c, wih1, whh0, whh1, up);
  prep_xe<<<256, 256, 0, stream>>>(xf, z, Wz, bz, bpr, xe);
  prep_state<<<2048, 256, 0, stream>>>(h0, (u16*)h0u, (u16*)h1u, flags);

  MainParams prm;
  prm.y0 = y0; prm.c0 = c0;
  prm.bih0 = bih0; prm.bhh0 = bhh0; prm.bih1 = bih1; prm.bhh1 = bhh1;
  prm.wproj = Wpr; prm.bproj = bpr;
  prm.xe = xe; prm.w0c = w0c; prm.wih1 = wih1; prm.whh0 = whh0;
  prm.whh1 = whh1; prm.up = up;
  prm.h0u = h0u; prm.h1u = h1u; prm.ypart = ypart; prm.flags = flags;
  prm.out = (float*)d_out;

  hipFuncSetAttribute((const void*)lstm_main, hipFuncAttributeMaxDynamicSharedMemorySize, LDS_TOTAL);
  void* args[] = { &prm };
  hipLaunchCooperativeKernel((void*)lstm_main, dim3(256), dim3(512), args, LDS_TOTAL, stream);
}